// Round 1
// 112.690 us; speedup vs baseline: 1.0995x; 1.0995x over previous
//
#include <hip/hip_runtime.h>
#include <hip/hip_bf16.h>

#define N_HALF 4096
#define M_TOT  8192
#define D      256
#define TJ     64          // j-rows staged in LDS per jt
#define JCHUNK 512         // j-cols per block
#define NJT    (JCHUNK / TJ)

typedef __attribute__((ext_vector_type(8))) short bf16x8;
typedef __attribute__((ext_vector_type(4))) float f32x4;
typedef __attribute__((address_space(1))) const unsigned int ga_u32;
typedef __attribute__((address_space(3))) unsigned int ls_u32;

__device__ __forceinline__ float wave_reduce_sum(float v) {
    v += __shfl_xor(v, 1);
    v += __shfl_xor(v, 2);
    v += __shfl_xor(v, 4);
    v += __shfl_xor(v, 8);
    v += __shfl_xor(v, 16);
    v += __shfl_xor(v, 32);
    return v;
}

// Fused: normalize both rows of pair r (reps row r = zjs[r], row r+N = zis[r]),
// compute the positive-pair dot in fp32, zero rowsum entries (safe: stream order
// guarantees k_prep completes before k_main's atomics).
__global__ void k_prep(const float* __restrict__ zis, const float* __restrict__ zjs,
                       __hip_bfloat16* __restrict__ zn, float* __restrict__ rowsum,
                       float* __restrict__ pos_part) {
    int r = blockIdx.x;        // 0..4095
    int t = threadIdx.x;       // 0..255
    float zi = zis[(size_t)r * D + t];
    float zj = zjs[(size_t)r * D + t];
    float ssi = wave_reduce_sum(zi * zi);
    float ssj = wave_reduce_sum(zj * zj);
    float dd  = wave_reduce_sum(zi * zj);
    __shared__ float red[3][4];
    int w = t >> 6;
    if ((t & 63) == 0) { red[0][w] = ssi; red[1][w] = ssj; red[2][w] = dd; }
    __syncthreads();
    float ni = fmaxf(sqrtf(red[0][0] + red[0][1] + red[0][2] + red[0][3]), 1e-8f);
    float nj = fmaxf(sqrtf(red[1][0] + red[1][1] + red[1][2] + red[1][3]), 1e-8f);
    zn[(size_t)r * D + t]            = __float2bfloat16(zj / nj);
    zn[(size_t)(r + N_HALF) * D + t] = __float2bfloat16(zi / ni);
    if (t == 0) {
        float dot = red[2][0] + red[2][1] + red[2][2] + red[2][3];
        // sum over all 2N rows of pos_i = sim/T ; each unordered pair twice -> *4
        pos_part[r] = dot / (ni * nj) * 4.0f;
        rowsum[r] = 0.0f;
        rowsum[r + N_HALF] = 0.0f;
    }
}

// 2-phase double-buffered pipeline (T3-minimum recipe):
//   prologue: STAGE(buf0, jt=0); barrier;
//   loop jt:  STAGE(buf^1, jt+1)  -- global_load_lds, issued BEFORE compute
//             compute buf          -- ds_read(swizzled) + MFMA + exp accumulate
//             barrier (drains vmcnt; loads had ~640 cyc of compute to land)
// LDS layout: linear [64][256] ushort rows (global_load_lds needs linear dest),
// bank-conflict fix via both-sides XOR swizzle on 16B units: pu = u ^ (row&7)
// (pre-swizzled GLOBAL source address + swizzled ds_read offset, m173 pattern).
__global__ __launch_bounds__(256, 2)
void k_main(const __hip_bfloat16* __restrict__ znh, float* __restrict__ rowsum) {
    __shared__ __align__(16) ushort zj0[TJ * D];   // 32768 B
    __shared__ __align__(16) ushort zj1[TJ * D];   // 32768 B
    const ushort* zn = reinterpret_cast<const ushort*>(znh);
    int tid  = threadIdx.x;
    int wave = tid >> 6;
    int lane = tid & 63;
    int q    = lane >> 4;   // quad
    int li   = lane & 15;
    int i_base = blockIdx.x * 256 + wave * 64;
    int j0     = blockIdx.y * JCHUNK;

    // A fragment (16x16x32 bf16): A[m][k], m = lane&15, k = quad*8 + j
    bf16x8 afrag[4][8];
#pragma unroll
    for (int it = 0; it < 4; ++it) {
        const ushort* ap = zn + (((size_t)(i_base + it * 16 + li)) << 8) + q * 8;
#pragma unroll
        for (int kt = 0; kt < 8; ++kt)
            afrag[it][kt] = *reinterpret_cast<const bf16x8*>(ap + kt * 32);
    }

    float part[4][4];   // [i_tile][reg-row]
#pragma unroll
    for (int it = 0; it < 4; ++it)
#pragma unroll
        for (int r = 0; r < 4; ++r) part[it][r] = 0.0f;

    // Per-lane swizzled ds_read offsets (ushort units). Row r = jtile*16+li,
    // r&7 == li&7 (16 = 0 mod 8), so the XOR term is jtile-invariant:
    // off = (r<<8) + (((kt*4+q) ^ (r&7)) * 8)
    int koff[8];
    {
        int swsh = (li & 7) << 3;
#pragma unroll
        for (int kt = 0; kt < 8; ++kt)
            koff[kt] = (((kt << 5) | (q << 3)) ^ swsh);
    }

    const ushort* rd = zj0;
    ushort*       wr = zj1;

    // -------- staging: 32 chunks of 1 KB; wave w issues chunks [w*8, w*8+8).
    // Chunk c holds rows 2c,2c+1. Lane l writes physical 16B-slot c*64+l, i.e.
    // row r = 2c + (l>>5), physical unit pu = l&31 -> fetch logical unit
    // u = pu ^ (r&7) from global so the read-side XOR lands on linear data.
#define STAGE(dstp, jbase)                                                       \
    {                                                                            \
        int c0 = wave * 8;                                                       \
        _Pragma("unroll")                                                        \
        for (int s = 0; s < 8; ++s) {                                            \
            int c = c0 + s;                                                      \
            int r = 2 * c + (lane >> 5);                                         \
            int u = (lane & 31) ^ (r & 7);                                       \
            const ushort* src = zn + (((size_t)((jbase) + r)) << 8) + (u << 3);  \
            __builtin_amdgcn_global_load_lds((ga_u32*)src,                       \
                                             (ls_u32*)((dstp) + c * 512),        \
                                             16, 0, 0);                          \
        }                                                                        \
    }

    STAGE(zj0, j0)
    __syncthreads();

    for (int jt = 0; jt < NJT; ++jt) {
        if (jt + 1 < NJT) STAGE(wr, j0 + (jt + 1) * TJ)

#pragma unroll
        for (int jtile = 0; jtile < 4; ++jtile) {
            f32x4 acc[4] = {{0,0,0,0},{0,0,0,0},{0,0,0,0},{0,0,0,0}};
            const ushort* jrow = rd + (jtile << 12) + (li << 8);
#pragma unroll
            for (int kt = 0; kt < 8; ++kt) {
                bf16x8 b = *reinterpret_cast<const bf16x8*>(jrow + koff[kt]);
#pragma unroll
                for (int it = 0; it < 4; ++it)
                    acc[it] = __builtin_amdgcn_mfma_f32_16x16x32_bf16(
                        afrag[it][kt], b, acc[it], 0, 0, 0);
            }
            // C/D layout (m89-verified): col = lane&15, row = quad*4 + reg
#pragma unroll
            for (int it = 0; it < 4; ++it)
#pragma unroll
                for (int r = 0; r < 4; ++r)
                    part[it][r] += __expf(acc[it][r] * 2.0f - 2.0f);
        }
        __syncthreads();   // staged tile ready; all reads of rd done
        const ushort* t0 = rd; rd = wr; wr = (ushort*)t0;
    }
#undef STAGE

    // Reduce across the 16 lanes holding different j-cols of the same rows.
#pragma unroll
    for (int it = 0; it < 4; ++it)
#pragma unroll
        for (int r = 0; r < 4; ++r) {
            float v = part[it][r];
            v += __shfl_xor(v, 1);
            v += __shfl_xor(v, 2);
            v += __shfl_xor(v, 4);
            v += __shfl_xor(v, 8);
            if (li == 0) atomicAdd(&rowsum[i_base + it * 16 + q * 4 + r], v);
        }
}

// lse_i = 2 + log(rowsum_i - 1); loss = (sum lse - sum pos)/M
__global__ void k_final(const float* __restrict__ rowsum, const float* __restrict__ pos_part,
                        float* __restrict__ out) {
    int t = threadIdx.x;
    float acc = 0.0f;
    for (int i = t; i < M_TOT; i += 256)
        acc += 2.0f + __logf(rowsum[i] - 1.0f);
    float pacc = 0.0f;
    for (int i = t; i < N_HALF; i += 256)
        pacc += pos_part[i];
    acc  = wave_reduce_sum(acc);
    pacc = wave_reduce_sum(pacc);
    __shared__ float wsum[4], psum[4];
    if ((t & 63) == 0) { wsum[t >> 6] = acc; psum[t >> 6] = pacc; }
    __syncthreads();
    if (t == 0) {
        float tot = wsum[0] + wsum[1] + wsum[2] + wsum[3];
        float pt  = psum[0] + psum[1] + psum[2] + psum[3];
        out[0] = (tot - pt) / (float)M_TOT;
    }
}

extern "C" void kernel_launch(void* const* d_in, const int* in_sizes, int n_in,
                              void* d_out, int out_size, void* d_ws, size_t ws_size,
                              hipStream_t stream) {
    const float* zis = (const float*)d_in[0];
    const float* zjs = (const float*)d_in[1];
    char* ws = (char*)d_ws;
    __hip_bfloat16* zn = (__hip_bfloat16*)ws;                         // 4 MB
    float* rowsum   = (float*)(ws + (size_t)M_TOT * D * 2);           // 32 KB
    float* pos_part = rowsum + M_TOT;                                 // 16 KB
    float* out = (float*)d_out;

    k_prep<<<N_HALF, 256, 0, stream>>>(zis, zjs, zn, rowsum, pos_part);
    dim3 grid(M_TOT / 256, M_TOT / JCHUNK);
    k_main<<<grid, 256, 0, stream>>>(zn, rowsum);
    k_final<<<1, 256, 0, stream>>>(rowsum, pos_part, out);
}